// Round 7
// baseline (357.120 us; speedup 1.0000x reference)
//
#include <hip/hip_runtime.h>
#include <hip/hip_bf16.h>

// GAT 2-layer. N=100000, L1: H=4,C=32 (HC=128), L2: H=1,C=32.
//
// R1: CSR gather instead of float-atomic scatter (1588 -> 826 us).
// R2: cooperative softmax via shfl broadcast (826 -> 734).
// R3: single-pass softmax, float4 loads, 8-deep unroll (734 -> 595).
// R4: atomic-free scatter; bf16 h payload; 16-deep unroll (595 -> 491).
// R5: both GEMMs -> bf16 MFMA 16x16x32, zero LDS/barriers (491 -> 443).
// R6: FAILED launch_bounds(256,8) -> scratch spills. Reverted.
// R7: gather1 = R4-exact body; gemm2 casts o1 fp32->bf16 in-register (~408).
// R8: two-phase 8-edge batches, hv[8] in flight, bf16 o1 (408 -> 363;
//     gather1 107 -> 75; VGPR 48, occ 47.5%).
// R9: FAILED hv[16]: VGPR 84 -> occ 28%. TLP loss > MLP gain.
// R10: FAILED 32 lanes/dst halves: occ 37.6%. R8 gather body = local opt.
// R11: fused gemm2 into gather1 (o1 via LDS, no global round-trip) +
//     fused hist into gemm1 (363 -> 347). Profile: gemm1_hist = 100us,
//     nothing busy (HBM 1.1TB/s, VALU 7%), WRITE 85MB = nominal 36MB +
//     ~49MB of 32B-granule atomic fabric RMWs. Fusion did NOT overlap
//     (hist blocks queue behind gemm blocks); hist is latency-serialized
//     (1 atomic-with-return per thread, 6642 trivial blocks).
// R12: unfuse gemm1/hist (decomposition + occupancy); hist_rank batched
//     8 edges/thread (int4 ei loads, 8 independent atomics in flight,
//     int4 rank writes); scatter batched 4 edges/thread. gather1+gemm2
//     fusion and R8 gather bodies unchanged.
//     (R12 resubmit: previous round hit GPUAcquisitionTimeout, never ran.)
// Self-loops are implicit: edge ids >= E map to (n,n).

typedef __bf16 bf16x8 __attribute__((ext_vector_type(8)));
typedef float f32x4 __attribute__((ext_vector_type(4)));

__device__ __forceinline__ float lrelu(float v) { return v >= 0.f ? v : 0.2f * v; }

__device__ __forceinline__ unsigned f2bf(float f) {   // RTNE f32->bf16 (finite inputs)
    unsigned u = __float_as_uint(f);
    return (u + 0x7FFFu + ((u >> 16) & 1u)) >> 16;
}

__device__ __forceinline__ bf16x8 as_bf16x8(uint4 u) {
    union { uint4 u; bf16x8 b; } c; c.u = u; return c.b;
}

__device__ __forceinline__ void bf16x8_fma(uint4 hv, float a, float* acc) {
    acc[0] = fmaf(a, __uint_as_float(hv.x << 16), acc[0]);
    acc[1] = fmaf(a, __uint_as_float(hv.x & 0xFFFF0000u), acc[1]);
    acc[2] = fmaf(a, __uint_as_float(hv.y << 16), acc[2]);
    acc[3] = fmaf(a, __uint_as_float(hv.y & 0xFFFF0000u), acc[3]);
    acc[4] = fmaf(a, __uint_as_float(hv.z << 16), acc[4]);
    acc[5] = fmaf(a, __uint_as_float(hv.z & 0xFFFF0000u), acc[5]);
    acc[6] = fmaf(a, __uint_as_float(hv.w << 16), acc[6]);
    acc[7] = fmaf(a, __uint_as_float(hv.w & 0xFFFF0000u), acc[7]);
}

// ---------------- weight cast: W1[128,128] -> w1t[c][k] bf16 ; W2 -> w2t[c][k]
__global__ __launch_bounds__(256) void cast_w_k(const float* __restrict__ W1,
                                                const float* __restrict__ W2,
                                                ushort* __restrict__ w1t,
                                                ushort* __restrict__ w2t) {
    int tid = blockIdx.x * 256 + threadIdx.x;
    if (tid < 16384) {
        int k = tid >> 7, c = tid & 127;
        w1t[c * 128 + k] = (ushort)f2bf(W1[tid]);
    }
    if (tid < 4096) {
        int k = tid >> 5, c = tid & 31;
        w2t[c * 128 + k] = (ushort)f2bf(W2[tid]);
    }
}

// ---------------- GEMM1 (MFMA): x[N,128]fp32 (cast in-reg) @ W1 -> h[N,128]bf16 + as/ad
// Block: 64 rows, 4 waves x 16 rows. 8 col-tiles, K=128 in 4 steps. No LDS.
__global__ __launch_bounds__(256) void gemm1_mfma(
    const float* __restrict__ x, const ushort* __restrict__ w1t,
    const float* __restrict__ atts, const float* __restrict__ attd,
    ushort* __restrict__ h, float* __restrict__ as_, float* __restrict__ ad_, int N) {
    const int w = threadIdx.x >> 6;
    const int l = threadIdx.x & 63;
    const int c15 = l & 15;
    const int quad = l >> 4;
    const int n_base = blockIdx.x * 64 + w * 16;
    const int n = n_base + c15;

    bf16x8 a[4];
    if (n < N) {
        const float4* xr = (const float4*)(x + (size_t)n * 128);
#pragma unroll
        for (int ks = 0; ks < 4; ks++) {
            float4 p0 = xr[ks * 8 + quad * 2];
            float4 p1 = xr[ks * 8 + quad * 2 + 1];
            uint4 u;
            u.x = f2bf(p0.x) | (f2bf(p0.y) << 16);
            u.y = f2bf(p0.z) | (f2bf(p0.w) << 16);
            u.z = f2bf(p1.x) | (f2bf(p1.y) << 16);
            u.w = f2bf(p1.z) | (f2bf(p1.w) << 16);
            a[ks] = as_bf16x8(u);
        }
    } else {
        uint4 z = make_uint4(0, 0, 0, 0);
#pragma unroll
        for (int ks = 0; ks < 4; ks++) a[ks] = as_bf16x8(z);
    }

    f32x4 acc[8];
#pragma unroll
    for (int ct = 0; ct < 8; ct++) acc[ct] = (f32x4){0.f, 0.f, 0.f, 0.f};

#pragma unroll
    for (int ct = 0; ct < 8; ct++) {
        const uint4* wr = (const uint4*)(w1t + (size_t)(ct * 16 + c15) * 128);
#pragma unroll
        for (int ks = 0; ks < 4; ks++) {
            bf16x8 bfrag = as_bf16x8(wr[ks * 4 + quad]);
            acc[ct] = __builtin_amdgcn_mfma_f32_16x16x32_bf16(a[ks], bfrag, acc[ct], 0, 0, 0);
        }
    }

#pragma unroll
    for (int ct = 0; ct < 8; ct++) {
        int col = ct * 16 + c15;
#pragma unroll
        for (int reg = 0; reg < 4; reg++) {
            int n_out = n_base + quad * 4 + reg;
            if (n_out < N) h[(size_t)n_out * 128 + col] = (ushort)f2bf(acc[ct][reg]);
        }
    }
#pragma unroll
    for (int hh = 0; hh < 4; hh++) {
        float sA = atts[hh * 32 + c15], sB = atts[hh * 32 + 16 + c15];
        float dA = attd[hh * 32 + c15], dB = attd[hh * 32 + 16 + c15];
#pragma unroll
        for (int reg = 0; reg < 4; reg++) {
            float ps = acc[2 * hh][reg] * sA + acc[2 * hh + 1][reg] * sB;
            float pd = acc[2 * hh][reg] * dA + acc[2 * hh + 1][reg] * dB;
            ps += __shfl_xor(ps, 1); pd += __shfl_xor(pd, 1);
            ps += __shfl_xor(ps, 2); pd += __shfl_xor(pd, 2);
            ps += __shfl_xor(ps, 4); pd += __shfl_xor(pd, 4);
            ps += __shfl_xor(ps, 8); pd += __shfl_xor(pd, 8);
            int n_out = n_base + quad * 4 + reg;
            if (c15 == 0 && n_out < N) { as_[n_out * 4 + hh] = ps; ad_[n_out * 4 + hh] = pd; }
        }
    }
}

// ---------------- edge histogram: 8 edges/thread, int4 loads, 8 independent
// atomics in flight per thread (latency hiding), int4 rank writes.
__global__ __launch_bounds__(256) void hist_rank_k(const int* __restrict__ ei, int E, int N,
                                                   int* __restrict__ deg, int* __restrict__ rank) {
    const int EN = E + N;
    const int base = (blockIdx.x * 256 + threadIdx.x) * 8;
    if (base >= EN) return;
    int dd[8];
    if (base + 8 <= E) {                       // fast path: vector loads of dst ids
        int4 a = *(const int4*)&ei[E + base];
        int4 c = *(const int4*)&ei[E + base + 4];
        dd[0] = a.x; dd[1] = a.y; dd[2] = a.z; dd[3] = a.w;
        dd[4] = c.x; dd[5] = c.y; dd[6] = c.z; dd[7] = c.w;
    } else {
#pragma unroll
        for (int k = 0; k < 8; k++) {
            int e = base + k;
            dd[k] = (e < EN) ? ((e < E) ? ei[E + e] : e - E) : 0;
        }
    }
    int rr[8];
#pragma unroll
    for (int k = 0; k < 8; k++) {              // independent -> pipelined RMWs
        int e = base + k;
        if (e < EN) rr[k] = atomicAdd(&deg[dd[k]], 1);
    }
    if (base + 8 <= EN) {
        *(int4*)&rank[base]     = make_int4(rr[0], rr[1], rr[2], rr[3]);
        *(int4*)&rank[base + 4] = make_int4(rr[4], rr[5], rr[6], rr[7]);
    } else {
#pragma unroll
        for (int k = 0; k < 8; k++) if (base + k < EN) rank[base + k] = rr[k];
    }
}

// ---------------- CSR build: scan -> atomic-free scatter ---------------------
__global__ __launch_bounds__(256) void scan1_k(const int* __restrict__ deg,
                                               int* __restrict__ tmp, int* __restrict__ partial, int N) {
    __shared__ int sh[256];
    int i = blockIdx.x * 256 + threadIdx.x;
    int v = (i < N) ? deg[i] : 0;
    sh[threadIdx.x] = v;
    __syncthreads();
#pragma unroll
    for (int off = 1; off < 256; off <<= 1) {
        int t = (threadIdx.x >= off) ? sh[threadIdx.x - off] : 0;
        __syncthreads();
        sh[threadIdx.x] += t;
        __syncthreads();
    }
    if (i < N) tmp[i] = sh[threadIdx.x];
    if (threadIdx.x == 255) partial[blockIdx.x] = sh[255];
}

__global__ __launch_bounds__(1024) void scan2_k(int* __restrict__ partial, int B) {
    __shared__ int sh[1024];
    int i = threadIdx.x;
    int v = (i < B) ? partial[i] : 0;
    sh[i] = v;
    __syncthreads();
#pragma unroll
    for (int off = 1; off < 1024; off <<= 1) {
        int t = (i >= off) ? sh[i - off] : 0;
        __syncthreads();
        sh[i] += t;
        __syncthreads();
    }
    if (i < B) partial[i] = sh[i] - v;   // exclusive
}

__global__ __launch_bounds__(256) void scan3_k(const int* __restrict__ tmp, const int* __restrict__ partial,
                                               int* __restrict__ rs, int N) {
    int i = blockIdx.x * 256 + threadIdx.x;
    if (i < N) rs[i + 1] = tmp[i] + partial[blockIdx.x];
    if (i == 0) rs[0] = 0;
}

// 4 edges/thread: independent random rs loads + csr stores in flight.
__global__ __launch_bounds__(256) void scatter_k(const int* __restrict__ ei, const int* __restrict__ rank,
                                                 const int* __restrict__ rs, int E, int N,
                                                 int* __restrict__ csr) {
    const int EN = E + N;
    const int base = (blockIdx.x * 256 + threadIdx.x) * 4;
    if (base >= EN) return;
#pragma unroll
    for (int k = 0; k < 4; k++) {
        int e = base + k;
        if (e < EN) {
            int s, d;
            if (e < E) { s = ei[e]; d = ei[E + e]; } else { s = e - E; d = s; }
            csr[rs[d] + rank[e]] = s;      // fire-and-forget random store
        }
    }
}

// ---------------- layer-1 gather (R8 loop) + fused GEMM2 epilogue.
// 16 lanes/dst, 8 bf16 ch/lane, two-phase 8-edge batches (R8-exact).
// Epilogue: pack o1 row to LDS (16 dsts x 16 uint4, padded), barrier,
// wave 0 runs gemm2 (8 MFMAs) + att-logit reduce for the block's 16 rows.
// No early return (barrier); d>=N lanes run an empty loop.
__global__ __launch_bounds__(256) void gather1_k(
    const int* __restrict__ rs, const int* __restrict__ csr,
    const float* __restrict__ as_, const float* __restrict__ ad_,
    const uint4* __restrict__ h, const float* __restrict__ b,
    const ushort* __restrict__ w2t, const float* __restrict__ atts2,
    const float* __restrict__ attd2,
    ushort* __restrict__ h2, float* __restrict__ as2, float* __restrict__ ad2,
    int N) {
    __shared__ uint4 o1s[16][18];        // [dst_local][ch-slot], +2 pad vs bank conflicts
    const int jj = threadIdx.x & 31;
    const int l16 = jj & 15;
    const int sub = jj & 16;             // 16-lane subgroup base in 32-window
    const int dl = (threadIdx.x >> 5) * 2 + (jj >> 4);   // 0..15
    const int d = blockIdx.x * 16 + dl;
    const int hl = l16 >> 2;             // my head
    const int sl = l16 & 3;              // my slot base
    int beg = 0, end = 0;
    float adv = 0.f;
    if (d < N) { beg = rs[d]; end = rs[d + 1]; adv = ad_[d * 4 + hl]; }

    float acc[8];
#pragma unroll
    for (int i = 0; i < 8; i++) acc[i] = 0.f;
    float den = 0.f;

    int j0 = beg;
    int sv0 = 0, sv1 = 0;
    float ex0 = 0.f, ex1 = 0.f;
    bool have = (j0 + 8 <= end);
    if (have) {
        sv0 = csr[j0 + sl];
        sv1 = csr[j0 + sl + 4];
        ex0 = __expf(fminf(lrelu(as_[sv0 * 4 + hl] + adv), 80.f));
        ex1 = __expf(fminf(lrelu(as_[sv1 * 4 + hl] + adv), 80.f));
    }
    while (have) {
        bool nhave = (j0 + 16 <= end);
        int na = nhave ? (j0 + 8) : beg;          // safe addr (deg>=8 here)
        int psv0 = csr[na + sl];
        int psv1 = csr[na + sl + 4];
        den += ex0 + ex1;
        float av[8]; uint4 hv[8];
#pragma unroll
        for (int e = 0; e < 8; e++) {
            const int k = e >> 2, q = e & 3;
            const int srcl = sub + (l16 & 12) + q;
            float exk = k ? ex1 : ex0;
            int   svk = k ? sv1 : sv0;
            av[e] = __shfl(exk, srcl, 32);
            int s = __shfl(svk, srcl, 32);
            hv[e] = h[(size_t)s * 16 + l16];
        }
        // next-chunk as_ loads: issued after hv so their wait leaves hv in flight
        float pex0 = __expf(fminf(lrelu(as_[psv0 * 4 + hl] + adv), 80.f));
        float pex1 = __expf(fminf(lrelu(as_[psv1 * 4 + hl] + adv), 80.f));
#pragma unroll
        for (int e = 0; e < 8; e++) bf16x8_fma(hv[e], av[e], acc);
        sv0 = psv0; sv1 = psv1; ex0 = pex0; ex1 = pex1;
        j0 += 8; have = nhave;
    }
    int r = end - j0;                    // 0..7
    if (r > 0) {
        float ex0r = 0.f, ex1r = 0.f;
        int   sv0r = 0,   sv1r = 0;
        if (sl < r) {
            sv0r = csr[j0 + sl];
            ex0r = __expf(fminf(lrelu(as_[sv0r * 4 + hl] + adv), 80.f));
            den += ex0r;
        }
        if (sl + 4 < r) {
            sv1r = csr[j0 + sl + 4];
            ex1r = __expf(fminf(lrelu(as_[sv1r * 4 + hl] + adv), 80.f));
            den += ex1r;
        }
        float av[8]; uint4 hv[8];
#pragma unroll
        for (int e = 0; e < 8; e++) {
            const int k = e >> 2, q = e & 3;
            const int srcl = sub + (l16 & 12) + q;
            float exk = k ? ex1r : ex0r;
            int   svk = k ? sv1r : sv0r;
            av[e] = __shfl(exk, srcl, 32);              // unguarded: src lanes active
            int s = __shfl(svk, srcl, 32);
            if (e < r) hv[e] = h[(size_t)s * 16 + l16]; // guarded: no garbage fetch
        }
#pragma unroll
        for (int e = 0; e < 8; e++) if (e < r) bf16x8_fma(hv[e], av[e], acc);
    }
    den += __shfl_xor(den, 1, 32);
    den += __shfl_xor(den, 2, 32);
    const float rcp = 1.f / (den + 1e-16f);
    float4 b0 = *(const float4*)&b[l16 * 8];
    float4 b1 = *(const float4*)&b[l16 * 8 + 4];
    float v0 = fmaxf(acc[0] * rcp + b0.x, 0.f);
    float v1 = fmaxf(acc[1] * rcp + b0.y, 0.f);
    float v2 = fmaxf(acc[2] * rcp + b0.z, 0.f);
    float v3 = fmaxf(acc[3] * rcp + b0.w, 0.f);
    float v4 = fmaxf(acc[4] * rcp + b1.x, 0.f);
    float v5 = fmaxf(acc[5] * rcp + b1.y, 0.f);
    float v6 = fmaxf(acc[6] * rcp + b1.z, 0.f);
    float v7 = fmaxf(acc[7] * rcp + b1.w, 0.f);
    uint4 pk;
    pk.x = f2bf(v0) | (f2bf(v1) << 16);
    pk.y = f2bf(v2) | (f2bf(v3) << 16);
    pk.z = f2bf(v4) | (f2bf(v5) << 16);
    pk.w = f2bf(v6) | (f2bf(v7) << 16);
    o1s[dl][l16] = pk;                   // o1 never touches global memory
    __syncthreads();

    // ---- fused GEMM2: wave 0 computes h2/as2/ad2 for the block's 16 rows
    if (threadIdx.x < 64) {
        const int l = threadIdx.x;
        const int c15g = l & 15;
        const int quad = l >> 4;
        bf16x8 a2[4];
#pragma unroll
        for (int ks = 0; ks < 4; ks++) a2[ks] = as_bf16x8(o1s[c15g][ks * 4 + quad]);
        f32x4 acc2[2];
#pragma unroll
        for (int ct = 0; ct < 2; ct++) acc2[ct] = (f32x4){0.f, 0.f, 0.f, 0.f};
#pragma unroll
        for (int ct = 0; ct < 2; ct++) {
            const uint4* wr = (const uint4*)(w2t + (size_t)(ct * 16 + c15g) * 128);
#pragma unroll
            for (int ks = 0; ks < 4; ks++) {
                bf16x8 bfrag = as_bf16x8(wr[ks * 4 + quad]);
                acc2[ct] = __builtin_amdgcn_mfma_f32_16x16x32_bf16(a2[ks], bfrag, acc2[ct], 0, 0, 0);
            }
        }
        const int nb = blockIdx.x * 16;
#pragma unroll
        for (int ct = 0; ct < 2; ct++) {
            int col = ct * 16 + c15g;
#pragma unroll
            for (int reg = 0; reg < 4; reg++) {
                int n_out = nb + quad * 4 + reg;
                if (n_out < N) h2[(size_t)n_out * 32 + col] = (ushort)f2bf(acc2[ct][reg]);
            }
        }
        float sA = atts2[c15g], sB = atts2[16 + c15g];
        float dA = attd2[c15g], dB = attd2[16 + c15g];
#pragma unroll
        for (int reg = 0; reg < 4; reg++) {
            float ps = acc2[0][reg] * sA + acc2[1][reg] * sB;
            float pd = acc2[0][reg] * dA + acc2[1][reg] * dB;
            ps += __shfl_xor(ps, 1); pd += __shfl_xor(pd, 1);
            ps += __shfl_xor(ps, 2); pd += __shfl_xor(pd, 2);
            ps += __shfl_xor(ps, 4); pd += __shfl_xor(pd, 4);
            ps += __shfl_xor(ps, 8); pd += __shfl_xor(pd, 8);
            int n_out = nb + quad * 4 + reg;
            if (c15g == 0 && n_out < N) { as2[n_out] = ps; ad2[n_out] = pd; }
        }
    }
}

// ---------------- layer-2 gather (R8-exact): 4 lanes/dst, 8 bf16 ch/lane.
__global__ __launch_bounds__(256) void gather2_k(
    const int* __restrict__ rs, const int* __restrict__ csr,
    const float* __restrict__ as_, const float* __restrict__ ad_,
    const uint4* __restrict__ h, const float* __restrict__ b,
    float* __restrict__ o, int N) {
    const int jj = threadIdx.x & 31;
    const int l4 = jj & 3;
    const int sub = jj & 28;             // 4-lane subgroup base
    const int d = blockIdx.x * 64 + (threadIdx.x >> 5) * 8 + (jj >> 2);
    if (d >= N) return;
    const int beg = rs[d], end = rs[d + 1];
    const float adv = ad_[d];

    float acc[8];
#pragma unroll
    for (int i = 0; i < 8; i++) acc[i] = 0.f;
    float den = 0.f;

    int j0 = beg;
    int sv0 = 0, sv1 = 0;
    float ex0 = 0.f, ex1 = 0.f;
    bool have = (j0 + 8 <= end);
    if (have) {
        sv0 = csr[j0 + l4];
        sv1 = csr[j0 + l4 + 4];
        ex0 = __expf(fminf(lrelu(as_[sv0] + adv), 80.f));
        ex1 = __expf(fminf(lrelu(as_[sv1] + adv), 80.f));
    }
    while (have) {
        bool nhave = (j0 + 16 <= end);
        int na = nhave ? (j0 + 8) : beg;
        int psv0 = csr[na + l4];
        int psv1 = csr[na + l4 + 4];
        den += ex0 + ex1;
        float av[8]; uint4 hv[8];
#pragma unroll
        for (int e = 0; e < 8; e++) {
            const int k = e >> 2, q = e & 3;
            const int srcl = sub + q;
            float exk = k ? ex1 : ex0;
            int   svk = k ? sv1 : sv0;
            av[e] = __shfl(exk, srcl, 32);
            int s = __shfl(svk, srcl, 32);
            hv[e] = h[(size_t)s * 4 + l4];
        }
        float pex0 = __expf(fminf(lrelu(as_[psv0] + adv), 80.f));
        float pex1 = __expf(fminf(lrelu(as_[psv1] + adv), 80.f));
#pragma unroll
        for (int e = 0; e < 8; e++) bf16x8_fma(hv[e], av[e], acc);
        sv0 = psv0; sv1 = psv1; ex0 = pex0; ex1 = pex1;
        j0 += 8; have = nhave;
    }
    int r = end - j0;                    // 0..7
    if (r > 0) {
        float ex0r = 0.f, ex1r = 0.f;
        int   sv0r = 0,   sv1r = 0;
        if (l4 < r) {
            sv0r = csr[j0 + l4];
            ex0r = __expf(fminf(lrelu(as_[sv0r] + adv), 80.f));
            den += ex0r;
        }
        if (l4 + 4 < r) {
            sv1r = csr[j0 + l4 + 4];
            ex1r = __expf(fminf(lrelu(as_[sv1r] + adv), 80.f));
            den += ex1r;
        }
        float av[8]; uint4 hv[8];
#pragma unroll
        for (int e = 0; e < 8; e++) {
            const int k = e >> 2, q = e & 3;
            const int srcl = sub + q;
            float exk = k ? ex1r : ex0r;
            int   svk = k ? sv1r : sv0r;
            av[e] = __shfl(exk, srcl, 32);              // unguarded
            int s = __shfl(svk, srcl, 32);
            if (e < r) hv[e] = h[(size_t)s * 4 + l4];   // guarded issue
        }
#pragma unroll
        for (int e = 0; e < 8; e++) if (e < r) bf16x8_fma(hv[e], av[e], acc);
    }
    den += __shfl_xor(den, 1, 32);
    den += __shfl_xor(den, 2, 32);
    const float rcp = 1.f / (den + 1e-16f);
    float4 b0 = *(const float4*)&b[l4 * 8];
    float4 b1 = *(const float4*)&b[l4 * 8 + 4];
    float4 o0, o1v;
    o0.x  = acc[0] * rcp + b0.x;
    o0.y  = acc[1] * rcp + b0.y;
    o0.z  = acc[2] * rcp + b0.z;
    o0.w  = acc[3] * rcp + b0.w;
    o1v.x = acc[4] * rcp + b1.x;
    o1v.y = acc[5] * rcp + b1.y;
    o1v.z = acc[6] * rcp + b1.z;
    o1v.w = acc[7] * rcp + b1.w;
    *(float4*)&o[(size_t)d * 32 + l4 * 8]     = o0;
    *(float4*)&o[(size_t)d * 32 + l4 * 8 + 4] = o1v;
}

extern "C" void kernel_launch(void* const* d_in, const int* in_sizes, int n_in,
                              void* d_out, int out_size, void* d_ws, size_t ws_size,
                              hipStream_t stream) {
    const float* x    = (const float*)d_in[0];
    const int*   ei   = (const int*)d_in[1];
    const float* W1   = (const float*)d_in[2];
    const float* as1v = (const float*)d_in[3];
    const float* ad1v = (const float*)d_in[4];
    const float* b1   = (const float*)d_in[5];
    const float* W2   = (const float*)d_in[6];
    const float* as2v = (const float*)d_in[7];
    const float* ad2v = (const float*)d_in[8];
    const float* b2   = (const float*)d_in[9];
    float* out = (float*)d_out;

    const int N = in_sizes[0] / 128;
    const int E = in_sizes[1] / 2;
    const int EN = E + N;
    const int B = (N + 255) / 256;   // scan chunks (must be <= 1024)

    // workspace layout
    char* base = (char*)d_ws;
    size_t o = 0;
    auto alloc = [&](size_t bytes) { void* p = base + o; o += (bytes + 255) & ~(size_t)255; return p; };
    ushort* w1t  = (ushort*)alloc((size_t)128 * 128 * 2);
    ushort* w2t  = (ushort*)alloc((size_t)32 * 128 * 2);
    ushort* h1   = (ushort*)alloc((size_t)N * 128 * 2);
    ushort* h2   = (ushort*)alloc((size_t)N * 32 * 2);
    float*  as1  = (float*)alloc((size_t)N * 4 * 4);
    float*  ad1  = (float*)alloc((size_t)N * 4 * 4);
    float*  as2  = (float*)alloc((size_t)N * 4);
    float*  ad2  = (float*)alloc((size_t)N * 4);
    int*    deg  = (int*)alloc((size_t)N * 4);
    int*    tmp  = (int*)alloc((size_t)N * 4);
    int*    part = (int*)alloc((size_t)1024 * 4);
    int*    rs   = (int*)alloc((size_t)(N + 1) * 4);
    int*    rank = (int*)alloc((size_t)EN * 4);
    int*    csr  = (int*)alloc((size_t)EN * 4);

    hipMemsetAsync(deg, 0, (size_t)N * 4, stream);

    const int nbE8 = ((EN + 7) / 8 + 255) / 256;   // hist blocks (8 edges/thread)
    const int nbE4 = ((EN + 3) / 4 + 255) / 256;   // scatter blocks (4 edges/thread)
    const int nbN = (N + 255) / 256;
    const int nbG = (N + 63) / 64;

    // ---- weight cast + layer-1 GEMM + CSR build
    cast_w_k<<<64, 256, 0, stream>>>(W1, W2, w1t, w2t);
    gemm1_mfma<<<nbG, 256, 0, stream>>>(x, w1t, as1v, ad1v, h1, as1, ad1, N);
    hist_rank_k<<<nbE8, 256, 0, stream>>>(ei, E, N, deg, rank);
    scan1_k<<<nbN, 256, 0, stream>>>(deg, tmp, part, N);
    scan2_k<<<1, 1024, 0, stream>>>(part, B);
    scan3_k<<<nbN, 256, 0, stream>>>(tmp, part, rs, N);
    scatter_k<<<nbE4, 256, 0, stream>>>(ei, rank, rs, E, N, csr);

    // ---- layer 1 edge softmax + aggregate + bias + relu + fused GEMM2
    gather1_k<<<(N + 15) / 16, 256, 0, stream>>>(rs, csr, as1, ad1, (const uint4*)h1, b1,
                                                 w2t, as2v, ad2v, h2, as2, ad2, N);

    // ---- layer 2 gather
    gather2_k<<<(N + 63) / 64, 256, 0, stream>>>(rs, csr, as2, ad2, (const uint4*)h2, b2, out, N);
}

// Round 9
// 321.710 us; speedup vs baseline: 1.1101x; 1.1101x over previous
//
#include <hip/hip_runtime.h>
#include <hip/hip_bf16.h>

// GAT 2-layer. N=100000, L1: H=4,C=32 (HC=128), L2: H=1,C=32.
//
// R1: CSR gather instead of float-atomic scatter (1588 -> 826 us).
// R2: cooperative softmax via shfl broadcast (826 -> 734).
// R3: single-pass softmax, float4 loads, 8-deep unroll (734 -> 595).
// R4: atomic-free scatter; bf16 h payload; 16-deep unroll (595 -> 491).
// R5: both GEMMs -> bf16 MFMA 16x16x32, zero LDS/barriers (491 -> 443).
// R6: FAILED launch_bounds(256,8) -> scratch spills. Reverted.
// R7: gather1 = R4-exact body; gemm2 casts o1 in-register (~408).
// R8: two-phase 8-edge batches, hv[8] in flight, bf16 o1 (408 -> 363).
// R9: FAILED hv[16]: VGPR 84 -> occ 28%. TLP loss > MLP gain.
// R10: FAILED 32 lanes/dst halves: occ 37.6%. R8 gather body = local opt.
// R11: gemm2 fused into gather1 (o1 via LDS); hist appended to gemm1
//     (363 -> 347). gemm1_hist = 100us = 45+55 back-to-back: appended
//     blocks do NOT overlap (CP issues in order).
// R12: unfused + 8-edge/thread hist batching: 357. Batching bought ~0 ->
//     hist is fabric atomic-THROUGHPUT-bound (1.7M device-scope RMWs at
//     32B granule execute at the fabric; per-XCD L2 non-coherent), not
//     latency-bound. gather1+gemm2 fusion confirmed good (74.9us, WRITE
//     25->7MB, MfmaUtil 0.42%).
// R13: hide the RMW wall under the GEMM: INTERLEAVE block types in one
//     dispatch (groups of 3 = 2 gemm + 1 hist, matching 1563:831), so
//     hist waves are co-resident with gemm waves from first CU-fill.
//     Disjoint pipes: MFMA/HBM-read vs fabric-RMW. Predict fused 55-70us.
//     (R13 resubmit: previous round hit GPUAcquisitionTimeout, never ran.)
// Self-loops are implicit: edge ids >= E map to (n,n).

typedef __bf16 bf16x8 __attribute__((ext_vector_type(8)));
typedef float f32x4 __attribute__((ext_vector_type(4)));

__device__ __forceinline__ float lrelu(float v) { return v >= 0.f ? v : 0.2f * v; }

__device__ __forceinline__ unsigned f2bf(float f) {   // RTNE f32->bf16 (finite inputs)
    unsigned u = __float_as_uint(f);
    return (u + 0x7FFFu + ((u >> 16) & 1u)) >> 16;
}

__device__ __forceinline__ bf16x8 as_bf16x8(uint4 u) {
    union { uint4 u; bf16x8 b; } c; c.u = u; return c.b;
}

__device__ __forceinline__ void bf16x8_fma(uint4 hv, float a, float* acc) {
    acc[0] = fmaf(a, __uint_as_float(hv.x << 16), acc[0]);
    acc[1] = fmaf(a, __uint_as_float(hv.x & 0xFFFF0000u), acc[1]);
    acc[2] = fmaf(a, __uint_as_float(hv.y << 16), acc[2]);
    acc[3] = fmaf(a, __uint_as_float(hv.y & 0xFFFF0000u), acc[3]);
    acc[4] = fmaf(a, __uint_as_float(hv.z << 16), acc[4]);
    acc[5] = fmaf(a, __uint_as_float(hv.z & 0xFFFF0000u), acc[5]);
    acc[6] = fmaf(a, __uint_as_float(hv.w << 16), acc[6]);
    acc[7] = fmaf(a, __uint_as_float(hv.w & 0xFFFF0000u), acc[7]);
}

// ---------------- weight cast: W1[128,128] -> w1t[c][k] bf16 ; W2 -> w2t[c][k]
__global__ __launch_bounds__(256) void cast_w_k(const float* __restrict__ W1,
                                                const float* __restrict__ W2,
                                                ushort* __restrict__ w1t,
                                                ushort* __restrict__ w2t) {
    int tid = blockIdx.x * 256 + threadIdx.x;
    if (tid < 16384) {
        int k = tid >> 7, c = tid & 127;
        w1t[c * 128 + k] = (ushort)f2bf(W1[tid]);
    }
    if (tid < 4096) {
        int k = tid >> 5, c = tid & 31;
        w2t[c * 128 + k] = (ushort)f2bf(W2[tid]);
    }
}

// ---------------- GEMM1 (MFMA) + INTERLEAVED edge histogram.
// Block groups of 3: r in {0,1} -> gemm block g*2+r; r==2 -> hist block g.
// Hist waves co-resident with gemm waves throughout the dispatch; fabric
// RMW throughput (hist) overlaps MFMA + HBM streaming (gemm).
__global__ __launch_bounds__(256) void gemm1_hist_k(
    const float* __restrict__ x, const ushort* __restrict__ w1t,
    const float* __restrict__ atts, const float* __restrict__ attd,
    ushort* __restrict__ h, float* __restrict__ as_, float* __restrict__ ad_,
    const int* __restrict__ ei, int* __restrict__ deg, int* __restrict__ rank,
    int N, int E, int nbG, int nbE8) {
    const int g = blockIdx.x / 3;
    const int r = blockIdx.x % 3;

    if (r == 2) {                          // ---- histogram path (8 edges/thread)
        if (g >= nbE8) return;
        const int EN = E + N;
        const int base = (g * 256 + threadIdx.x) * 8;
        if (base >= EN) return;
        int dd[8];
        if (base + 8 <= E) {               // fast path: vector loads of dst ids
            int4 a = *(const int4*)&ei[E + base];
            int4 c = *(const int4*)&ei[E + base + 4];
            dd[0] = a.x; dd[1] = a.y; dd[2] = a.z; dd[3] = a.w;
            dd[4] = c.x; dd[5] = c.y; dd[6] = c.z; dd[7] = c.w;
        } else {
#pragma unroll
            for (int k = 0; k < 8; k++) {
                int e = base + k;
                dd[k] = (e < EN) ? ((e < E) ? ei[E + e] : e - E) : 0;
            }
        }
        int rr[8];
#pragma unroll
        for (int k = 0; k < 8; k++) {      // independent -> pipelined RMWs
            int e = base + k;
            if (e < EN) rr[k] = atomicAdd(&deg[dd[k]], 1);
        }
        if (base + 8 <= EN) {
            *(int4*)&rank[base]     = make_int4(rr[0], rr[1], rr[2], rr[3]);
            *(int4*)&rank[base + 4] = make_int4(rr[4], rr[5], rr[6], rr[7]);
        } else {
#pragma unroll
            for (int k = 0; k < 8; k++) if (base + k < EN) rank[base + k] = rr[k];
        }
        return;
    }

    // ---- GEMM path (R5 body, unchanged)
    const int gb = g * 2 + r;              // gemm block id
    if (gb >= nbG) return;
    const int w = threadIdx.x >> 6;
    const int l = threadIdx.x & 63;
    const int c15 = l & 15;
    const int quad = l >> 4;
    const int n_base = gb * 64 + w * 16;
    const int n = n_base + c15;

    bf16x8 a[4];
    if (n < N) {
        const float4* xr = (const float4*)(x + (size_t)n * 128);
#pragma unroll
        for (int ks = 0; ks < 4; ks++) {
            float4 p0 = xr[ks * 8 + quad * 2];
            float4 p1 = xr[ks * 8 + quad * 2 + 1];
            uint4 u;
            u.x = f2bf(p0.x) | (f2bf(p0.y) << 16);
            u.y = f2bf(p0.z) | (f2bf(p0.w) << 16);
            u.z = f2bf(p1.x) | (f2bf(p1.y) << 16);
            u.w = f2bf(p1.z) | (f2bf(p1.w) << 16);
            a[ks] = as_bf16x8(u);
        }
    } else {
        uint4 z = make_uint4(0, 0, 0, 0);
#pragma unroll
        for (int ks = 0; ks < 4; ks++) a[ks] = as_bf16x8(z);
    }

    f32x4 acc[8];
#pragma unroll
    for (int ct = 0; ct < 8; ct++) acc[ct] = (f32x4){0.f, 0.f, 0.f, 0.f};

#pragma unroll
    for (int ct = 0; ct < 8; ct++) {
        const uint4* wr = (const uint4*)(w1t + (size_t)(ct * 16 + c15) * 128);
#pragma unroll
        for (int ks = 0; ks < 4; ks++) {
            bf16x8 bfrag = as_bf16x8(wr[ks * 4 + quad]);
            acc[ct] = __builtin_amdgcn_mfma_f32_16x16x32_bf16(a[ks], bfrag, acc[ct], 0, 0, 0);
        }
    }

#pragma unroll
    for (int ct = 0; ct < 8; ct++) {
        int col = ct * 16 + c15;
#pragma unroll
        for (int reg = 0; reg < 4; reg++) {
            int n_out = n_base + quad * 4 + reg;
            if (n_out < N) h[(size_t)n_out * 128 + col] = (ushort)f2bf(acc[ct][reg]);
        }
    }
#pragma unroll
    for (int hh = 0; hh < 4; hh++) {
        float sA = atts[hh * 32 + c15], sB = atts[hh * 32 + 16 + c15];
        float dA = attd[hh * 32 + c15], dB = attd[hh * 32 + 16 + c15];
#pragma unroll
        for (int reg = 0; reg < 4; reg++) {
            float ps = acc[2 * hh][reg] * sA + acc[2 * hh + 1][reg] * sB;
            float pd = acc[2 * hh][reg] * dA + acc[2 * hh + 1][reg] * dB;
            ps += __shfl_xor(ps, 1); pd += __shfl_xor(pd, 1);
            ps += __shfl_xor(ps, 2); pd += __shfl_xor(pd, 2);
            ps += __shfl_xor(ps, 4); pd += __shfl_xor(pd, 4);
            ps += __shfl_xor(ps, 8); pd += __shfl_xor(pd, 8);
            int n_out = n_base + quad * 4 + reg;
            if (c15 == 0 && n_out < N) { as_[n_out * 4 + hh] = ps; ad_[n_out * 4 + hh] = pd; }
        }
    }
}

// ---------------- CSR build: scan -> atomic-free scatter ---------------------
__global__ __launch_bounds__(256) void scan1_k(const int* __restrict__ deg,
                                               int* __restrict__ tmp, int* __restrict__ partial, int N) {
    __shared__ int sh[256];
    int i = blockIdx.x * 256 + threadIdx.x;
    int v = (i < N) ? deg[i] : 0;
    sh[threadIdx.x] = v;
    __syncthreads();
#pragma unroll
    for (int off = 1; off < 256; off <<= 1) {
        int t = (threadIdx.x >= off) ? sh[threadIdx.x - off] : 0;
        __syncthreads();
        sh[threadIdx.x] += t;
        __syncthreads();
    }
    if (i < N) tmp[i] = sh[threadIdx.x];
    if (threadIdx.x == 255) partial[blockIdx.x] = sh[255];
}

__global__ __launch_bounds__(1024) void scan2_k(int* __restrict__ partial, int B) {
    __shared__ int sh[1024];
    int i = threadIdx.x;
    int v = (i < B) ? partial[i] : 0;
    sh[i] = v;
    __syncthreads();
#pragma unroll
    for (int off = 1; off < 1024; off <<= 1) {
        int t = (i >= off) ? sh[i - off] : 0;
        __syncthreads();
        sh[i] += t;
        __syncthreads();
    }
    if (i < B) partial[i] = sh[i] - v;   // exclusive
}

__global__ __launch_bounds__(256) void scan3_k(const int* __restrict__ tmp, const int* __restrict__ partial,
                                               int* __restrict__ rs, int N) {
    int i = blockIdx.x * 256 + threadIdx.x;
    if (i < N) rs[i + 1] = tmp[i] + partial[blockIdx.x];
    if (i == 0) rs[0] = 0;
}

// 4 edges/thread: independent random rs loads + csr stores in flight.
__global__ __launch_bounds__(256) void scatter_k(const int* __restrict__ ei, const int* __restrict__ rank,
                                                 const int* __restrict__ rs, int E, int N,
                                                 int* __restrict__ csr) {
    const int EN = E + N;
    const int base = (blockIdx.x * 256 + threadIdx.x) * 4;
    if (base >= EN) return;
#pragma unroll
    for (int k = 0; k < 4; k++) {
        int e = base + k;
        if (e < EN) {
            int s, d;
            if (e < E) { s = ei[e]; d = ei[E + e]; } else { s = e - E; d = s; }
            csr[rs[d] + rank[e]] = s;      // fire-and-forget random store
        }
    }
}

// ---------------- layer-1 gather (R8 loop) + fused GEMM2 epilogue.
// 16 lanes/dst, 8 bf16 ch/lane, two-phase 8-edge batches (R8-exact).
// Epilogue: pack o1 row to LDS (16 dsts x 16 uint4, padded), barrier,
// wave 0 runs gemm2 (8 MFMAs) + att-logit reduce for the block's 16 rows.
// No early return (barrier); d>=N lanes run an empty loop.
__global__ __launch_bounds__(256) void gather1_k(
    const int* __restrict__ rs, const int* __restrict__ csr,
    const float* __restrict__ as_, const float* __restrict__ ad_,
    const uint4* __restrict__ h, const float* __restrict__ b,
    const ushort* __restrict__ w2t, const float* __restrict__ atts2,
    const float* __restrict__ attd2,
    ushort* __restrict__ h2, float* __restrict__ as2, float* __restrict__ ad2,
    int N) {
    __shared__ uint4 o1s[16][18];        // [dst_local][ch-slot], +2 pad vs bank conflicts
    const int jj = threadIdx.x & 31;
    const int l16 = jj & 15;
    const int sub = jj & 16;             // 16-lane subgroup base in 32-window
    const int dl = (threadIdx.x >> 5) * 2 + (jj >> 4);   // 0..15
    const int d = blockIdx.x * 16 + dl;
    const int hl = l16 >> 2;             // my head
    const int sl = l16 & 3;              // my slot base
    int beg = 0, end = 0;
    float adv = 0.f;
    if (d < N) { beg = rs[d]; end = rs[d + 1]; adv = ad_[d * 4 + hl]; }

    float acc[8];
#pragma unroll
    for (int i = 0; i < 8; i++) acc[i] = 0.f;
    float den = 0.f;

    int j0 = beg;
    int sv0 = 0, sv1 = 0;
    float ex0 = 0.f, ex1 = 0.f;
    bool have = (j0 + 8 <= end);
    if (have) {
        sv0 = csr[j0 + sl];
        sv1 = csr[j0 + sl + 4];
        ex0 = __expf(fminf(lrelu(as_[sv0 * 4 + hl] + adv), 80.f));
        ex1 = __expf(fminf(lrelu(as_[sv1 * 4 + hl] + adv), 80.f));
    }
    while (have) {
        bool nhave = (j0 + 16 <= end);
        int na = nhave ? (j0 + 8) : beg;          // safe addr (deg>=8 here)
        int psv0 = csr[na + sl];
        int psv1 = csr[na + sl + 4];
        den += ex0 + ex1;
        float av[8]; uint4 hv[8];
#pragma unroll
        for (int e = 0; e < 8; e++) {
            const int k = e >> 2, q = e & 3;
            const int srcl = sub + (l16 & 12) + q;
            float exk = k ? ex1 : ex0;
            int   svk = k ? sv1 : sv0;
            av[e] = __shfl(exk, srcl, 32);
            int s = __shfl(svk, srcl, 32);
            hv[e] = h[(size_t)s * 16 + l16];
        }
        // next-chunk as_ loads: issued after hv so their wait leaves hv in flight
        float pex0 = __expf(fminf(lrelu(as_[psv0 * 4 + hl] + adv), 80.f));
        float pex1 = __expf(fminf(lrelu(as_[psv1 * 4 + hl] + adv), 80.f));
#pragma unroll
        for (int e = 0; e < 8; e++) bf16x8_fma(hv[e], av[e], acc);
        sv0 = psv0; sv1 = psv1; ex0 = pex0; ex1 = pex1;
        j0 += 8; have = nhave;
    }
    int r = end - j0;                    // 0..7
    if (r > 0) {
        float ex0r = 0.f, ex1r = 0.f;
        int   sv0r = 0,   sv1r = 0;
        if (sl < r) {
            sv0r = csr[j0 + sl];
            ex0r = __expf(fminf(lrelu(as_[sv0r * 4 + hl] + adv), 80.f));
            den += ex0r;
        }
        if (sl + 4 < r) {
            sv1r = csr[j0 + sl + 4];
            ex1r = __expf(fminf(lrelu(as_[sv1r * 4 + hl] + adv), 80.f));
            den += ex1r;
        }
        float av[8]; uint4 hv[8];
#pragma unroll
        for (int e = 0; e < 8; e++) {
            const int k = e >> 2, q = e & 3;
            const int srcl = sub + (l16 & 12) + q;
            float exk = k ? ex1r : ex0r;
            int   svk = k ? sv1r : sv0r;
            av[e] = __shfl(exk, srcl, 32);              // unguarded: src lanes active
            int s = __shfl(svk, srcl, 32);
            if (e < r) hv[e] = h[(size_t)s * 16 + l16]; // guarded: no garbage fetch
        }
#pragma unroll
        for (int e = 0; e < 8; e++) if (e < r) bf16x8_fma(hv[e], av[e], acc);
    }
    den += __shfl_xor(den, 1, 32);
    den += __shfl_xor(den, 2, 32);
    const float rcp = 1.f / (den + 1e-16f);
    float4 b0 = *(const float4*)&b[l16 * 8];
    float4 b1 = *(const float4*)&b[l16 * 8 + 4];
    float v0 = fmaxf(acc[0] * rcp + b0.x, 0.f);
    float v1 = fmaxf(acc[1] * rcp + b0.y, 0.f);
    float v2 = fmaxf(acc[2] * rcp + b0.z, 0.f);
    float v3 = fmaxf(acc[3] * rcp + b0.w, 0.f);
    float v4 = fmaxf(acc[4] * rcp + b1.x, 0.f);
    float v5 = fmaxf(acc[5] * rcp + b1.y, 0.f);
    float v6 = fmaxf(acc[6] * rcp + b1.z, 0.f);
    float v7 = fmaxf(acc[7] * rcp + b1.w, 0.f);
    uint4 pk;
    pk.x = f2bf(v0) | (f2bf(v1) << 16);
    pk.y = f2bf(v2) | (f2bf(v3) << 16);
    pk.z = f2bf(v4) | (f2bf(v5) << 16);
    pk.w = f2bf(v6) | (f2bf(v7) << 16);
    o1s[dl][l16] = pk;                   // o1 never touches global memory
    __syncthreads();

    // ---- fused GEMM2: wave 0 computes h2/as2/ad2 for the block's 16 rows
    if (threadIdx.x < 64) {
        const int l = threadIdx.x;
        const int c15g = l & 15;
        const int quad = l >> 4;
        bf16x8 a2[4];
#pragma unroll
        for (int ks = 0; ks < 4; ks++) a2[ks] = as_bf16x8(o1s[c15g][ks * 4 + quad]);
        f32x4 acc2[2];
#pragma unroll
        for (int ct = 0; ct < 2; ct++) acc2[ct] = (f32x4){0.f, 0.f, 0.f, 0.f};
#pragma unroll
        for (int ct = 0; ct < 2; ct++) {
            const uint4* wr = (const uint4*)(w2t + (size_t)(ct * 16 + c15g) * 128);
#pragma unroll
            for (int ks = 0; ks < 4; ks++) {
                bf16x8 bfrag = as_bf16x8(wr[ks * 4 + quad]);
                acc2[ct] = __builtin_amdgcn_mfma_f32_16x16x32_bf16(a2[ks], bfrag, acc2[ct], 0, 0, 0);
            }
        }
        const int nb = blockIdx.x * 16;
#pragma unroll
        for (int ct = 0; ct < 2; ct++) {
            int col = ct * 16 + c15g;
#pragma unroll
            for (int reg = 0; reg < 4; reg++) {
                int n_out = nb + quad * 4 + reg;
                if (n_out < N) h2[(size_t)n_out * 32 + col] = (ushort)f2bf(acc2[ct][reg]);
            }
        }
        float sA = atts2[c15g], sB = atts2[16 + c15g];
        float dA = attd2[c15g], dB = attd2[16 + c15g];
#pragma unroll
        for (int reg = 0; reg < 4; reg++) {
            float ps = acc2[0][reg] * sA + acc2[1][reg] * sB;
            float pd = acc2[0][reg] * dA + acc2[1][reg] * dB;
            ps += __shfl_xor(ps, 1); pd += __shfl_xor(pd, 1);
            ps += __shfl_xor(ps, 2); pd += __shfl_xor(pd, 2);
            ps += __shfl_xor(ps, 4); pd += __shfl_xor(pd, 4);
            ps += __shfl_xor(ps, 8); pd += __shfl_xor(pd, 8);
            int n_out = nb + quad * 4 + reg;
            if (c15g == 0 && n_out < N) { as2[n_out] = ps; ad2[n_out] = pd; }
        }
    }
}

// ---------------- layer-2 gather (R8-exact): 4 lanes/dst, 8 bf16 ch/lane.
__global__ __launch_bounds__(256) void gather2_k(
    const int* __restrict__ rs, const int* __restrict__ csr,
    const float* __restrict__ as_, const float* __restrict__ ad_,
    const uint4* __restrict__ h, const float* __restrict__ b,
    float* __restrict__ o, int N) {
    const int jj = threadIdx.x & 31;
    const int l4 = jj & 3;
    const int sub = jj & 28;             // 4-lane subgroup base
    const int d = blockIdx.x * 64 + (threadIdx.x >> 5) * 8 + (jj >> 2);
    if (d >= N) return;
    const int beg = rs[d], end = rs[d + 1];
    const float adv = ad_[d];

    float acc[8];
#pragma unroll
    for (int i = 0; i < 8; i++) acc[i] = 0.f;
    float den = 0.f;

    int j0 = beg;
    int sv0 = 0, sv1 = 0;
    float ex0 = 0.f, ex1 = 0.f;
    bool have = (j0 + 8 <= end);
    if (have) {
        sv0 = csr[j0 + l4];
        sv1 = csr[j0 + l4 + 4];
        ex0 = __expf(fminf(lrelu(as_[sv0] + adv), 80.f));
        ex1 = __expf(fminf(lrelu(as_[sv1] + adv), 80.f));
    }
    while (have) {
        bool nhave = (j0 + 16 <= end);
        int na = nhave ? (j0 + 8) : beg;
        int psv0 = csr[na + l4];
        int psv1 = csr[na + l4 + 4];
        den += ex0 + ex1;
        float av[8]; uint4 hv[8];
#pragma unroll
        for (int e = 0; e < 8; e++) {
            const int k = e >> 2, q = e & 3;
            const int srcl = sub + q;
            float exk = k ? ex1 : ex0;
            int   svk = k ? sv1 : sv0;
            av[e] = __shfl(exk, srcl, 32);
            int s = __shfl(svk, srcl, 32);
            hv[e] = h[(size_t)s * 4 + l4];
        }
        float pex0 = __expf(fminf(lrelu(as_[psv0] + adv), 80.f));
        float pex1 = __expf(fminf(lrelu(as_[psv1] + adv), 80.f));
#pragma unroll
        for (int e = 0; e < 8; e++) bf16x8_fma(hv[e], av[e], acc);
        sv0 = psv0; sv1 = psv1; ex0 = pex0; ex1 = pex1;
        j0 += 8; have = nhave;
    }
    int r = end - j0;                    // 0..7
    if (r > 0) {
        float ex0r = 0.f, ex1r = 0.f;
        int   sv0r = 0,   sv1r = 0;
        if (l4 < r) {
            sv0r = csr[j0 + l4];
            ex0r = __expf(fminf(lrelu(as_[sv0r] + adv), 80.f));
            den += ex0r;
        }
        if (l4 + 4 < r) {
            sv1r = csr[j0 + l4 + 4];
            ex1r = __expf(fminf(lrelu(as_[sv1r] + adv), 80.f));
            den += ex1r;
        }
        float av[8]; uint4 hv[8];
#pragma unroll
        for (int e = 0; e < 8; e++) {
            const int k = e >> 2, q = e & 3;
            const int srcl = sub + q;
            float exk = k ? ex1r : ex0r;
            int   svk = k ? sv1r : sv0r;
            av[e] = __shfl(exk, srcl, 32);              // unguarded
            int s = __shfl(svk, srcl, 32);
            if (e < r) hv[e] = h[(size_t)s * 4 + l4];   // guarded issue
        }
#pragma unroll
        for (int e = 0; e < 8; e++) if (e < r) bf16x8_fma(hv[e], av[e], acc);
    }
    den += __shfl_xor(den, 1, 32);
    den += __shfl_xor(den, 2, 32);
    const float rcp = 1.f / (den + 1e-16f);
    float4 b0 = *(const float4*)&b[l4 * 8];
    float4 b1 = *(const float4*)&b[l4 * 8 + 4];
    float4 o0, o1v;
    o0.x  = acc[0] * rcp + b0.x;
    o0.y  = acc[1] * rcp + b0.y;
    o0.z  = acc[2] * rcp + b0.z;
    o0.w  = acc[3] * rcp + b0.w;
    o1v.x = acc[4] * rcp + b1.x;
    o1v.y = acc[5] * rcp + b1.y;
    o1v.z = acc[6] * rcp + b1.z;
    o1v.w = acc[7] * rcp + b1.w;
    *(float4*)&o[(size_t)d * 32 + l4 * 8]     = o0;
    *(float4*)&o[(size_t)d * 32 + l4 * 8 + 4] = o1v;
}

extern "C" void kernel_launch(void* const* d_in, const int* in_sizes, int n_in,
                              void* d_out, int out_size, void* d_ws, size_t ws_size,
                              hipStream_t stream) {
    const float* x    = (const float*)d_in[0];
    const int*   ei   = (const int*)d_in[1];
    const float* W1   = (const float*)d_in[2];
    const float* as1v = (const float*)d_in[3];
    const float* ad1v = (const float*)d_in[4];
    const float* b1   = (const float*)d_in[5];
    const float* W2   = (const float*)d_in[6];
    const float* as2v = (const float*)d_in[7];
    const float* ad2v = (const float*)d_in[8];
    const float* b2   = (const float*)d_in[9];
    float* out = (float*)d_out;

    const int N = in_sizes[0] / 128;
    const int E = in_sizes[1] / 2;
    const int EN = E + N;
    const int B = (N + 255) / 256;   // scan chunks (must be <= 1024)

    // workspace layout
    char* base = (char*)d_ws;
    size_t o = 0;
    auto alloc = [&](size_t bytes) { void* p = base + o; o += (bytes + 255) & ~(size_t)255; return p; };
    ushort* w1t  = (ushort*)alloc((size_t)128 * 128 * 2);
    ushort* w2t  = (ushort*)alloc((size_t)32 * 128 * 2);
    ushort* h1   = (ushort*)alloc((size_t)N * 128 * 2);
    ushort* h2   = (ushort*)alloc((size_t)N * 32 * 2);
    float*  as1  = (float*)alloc((size_t)N * 4 * 4);
    float*  ad1  = (float*)alloc((size_t)N * 4 * 4);
    float*  as2  = (float*)alloc((size_t)N * 4);
    float*  ad2  = (float*)alloc((size_t)N * 4);
    int*    deg  = (int*)alloc((size_t)N * 4);
    int*    tmp  = (int*)alloc((size_t)N * 4);
    int*    part = (int*)alloc((size_t)1024 * 4);
    int*    rs   = (int*)alloc((size_t)(N + 1) * 4);
    int*    rank = (int*)alloc((size_t)EN * 4);
    int*    csr  = (int*)alloc((size_t)EN * 4);

    hipMemsetAsync(deg, 0, (size_t)N * 4, stream);

    const int nbE8 = ((EN + 7) / 8 + 255) / 256;   // hist blocks (8 edges/thread)
    const int nbE4 = ((EN + 3) / 4 + 255) / 256;   // scatter blocks (4 edges/thread)
    const int nbN = (N + 255) / 256;
    const int nbG = (N + 63) / 64;

    // interleaved fused grid: groups of 3 = 2 gemm + 1 hist
    const int ngrp = max((nbG + 1) / 2, nbE8);

    // ---- weight cast, then fused [layer-1 GEMM || edge histogram]
    cast_w_k<<<64, 256, 0, stream>>>(W1, W2, w1t, w2t);
    gemm1_hist_k<<<ngrp * 3, 256, 0, stream>>>(x, w1t, as1v, ad1v, h1, as1, ad1,
                                               ei, deg, rank, N, E, nbG, nbE8);
    scan1_k<<<nbN, 256, 0, stream>>>(deg, tmp, part, N);
    scan2_k<<<1, 1024, 0, stream>>>(part, B);
    scan3_k<<<nbN, 256, 0, stream>>>(tmp, part, rs, N);
    scatter_k<<<nbE4, 256, 0, stream>>>(ei, rank, rs, E, N, csr);

    // ---- layer 1 edge softmax + aggregate + bias + relu + fused GEMM2
    gather1_k<<<(N + 15) / 16, 256, 0, stream>>>(rs, csr, as1, ad1, (const uint4*)h1, b1,
                                                 w2t, as2v, ad2v, h2, as2, ad2, N);

    // ---- layer 2 gather
    gather2_k<<<(N + 63) / 64, 256, 0, stream>>>(rs, csr, as2, ad2, (const uint4*)h2, b2, out, N);
}